// Round 10
// baseline (169.844 us; speedup 1.0000x reference)
//
#include <hip/hip_runtime.h>
#include <stdint.h>

#define N_NODES 50000
#define N_EDGES 1600000
#define N_FEAT 128
#define CAP 64            // final bucket slots per row; Poisson(28.8) mean, +6.5 sigma
#define OVF_CAP 65536     // overflow list capacity (expected usage: ~0, dormant)

// partition parameters
#define RSHIFT 8          // 256 rows per bucket
#define BROWS 256
#define NB 196            // ceil(50000 / 256)
#define NWG_A 256         // pass-A workgroups
#define A_THREADS 1024    // 4 waves/SIMD
#define EPW (N_EDGES / NWG_A)   // 6250 edges per pass-A workgroup
#define CSTRIDE 6272      // coarse entries per wg window (>= EPW, 256B-aligned) -> NO overflow possible

// ---------------- threefry2x32 (bit-exact, KAT-verified vs Random123) ----------

struct KeyPair { uint32_t a, b; };

__host__ __device__ constexpr inline uint32_t rotl32(uint32_t x, int r) {
  return (x << r) | (x >> (32 - r));
}

__host__ __device__ constexpr inline KeyPair threefry2x32(uint32_t k0, uint32_t k1,
                                                          uint32_t x0, uint32_t x1) {
  const uint32_t ks0 = k0, ks1 = k1, ks2 = k0 ^ k1 ^ 0x1BD11BDAu;
  x0 += ks0;
  x1 += ks1;
  const int rotA[4] = {13, 15, 26, 6};
  const int rotB[4] = {17, 29, 16, 24};
  const uint32_t ks[3] = {ks0, ks1, ks2};
  for (int i = 0; i < 5; ++i) {
    const int* rot = (i & 1) ? rotB : rotA;
    for (int j = 0; j < 4; ++j) {
      x0 += x1;
      x1 = rotl32(x1, rot[j]);
      x1 ^= x0;
    }
    x0 += ks[(i + 1) % 3];
    x1 += ks[(i + 2) % 3] + (uint32_t)(i + 1);
  }
  return {x0, x1};
}

// mask_key = fold_in(key(42), 7); compile-time.
constexpr KeyPair MASK_KEY = threefry2x32(0u, 42u, 0u, 7u);

// Partitionable (counter-mode) random_bits: element i -> threefry(key, (0, i)), bits = b1^b2.
__device__ inline bool edge_keep(uint32_t e) {
  KeyPair r = threefry2x32(MASK_KEY.a, MASK_KEY.b, 0u, e);
  uint32_t bits = r.a ^ r.b;
  float u = __uint_as_float((bits >> 9) | 0x3f800000u) - 1.0f;
  return u < 0.9f;
}

// fp32 bits -> bf16 with round-to-nearest-even
__device__ inline uint32_t f2bf(uint32_t b) {
  return (b + 0x7fffu + ((b >> 16) & 1u)) >> 16;
}

// =================== PRIMARY PATH ==============================================
// coarse entry (u64): (row << 48) | (col << 32) | f32bits(val)
// final payload (u32): (col << 16) | bf16bits(val)

// Fused conv + pass A (count -> scan -> DENSE place).
// Each wg packs its kept edges contiguously into a private 50 KB window:
// dense writes -> L2-merged full-line writebacks (kills the 92 MB write-amp).
// Capacity = slice size, so segment overflow is structurally impossible.
__global__ void __launch_bounds__(A_THREADS) convA_kernel(const float* __restrict__ x,
                                                          uint32_t* __restrict__ xb,
                                                          const float* __restrict__ adj_vals,
                                                          const int* __restrict__ row,
                                                          const int* __restrict__ col,
                                                          uint64_t* __restrict__ coarse,
                                                          uint32_t* __restrict__ lens,
                                                          uint32_t* __restrict__ segbase) {
  __shared__ uint32_t cnt[NB];
  __shared__ uint32_t base[NB];
  __shared__ uint32_t fill[NB];
  __shared__ uint32_t s[NB];
  int wg = blockIdx.x;
  int tid = threadIdx.x;
  if (tid < NB) { cnt[tid] = 0; fill[tid] = 0; }

  // phase 0: x -> bf16 slice (grid-stride, independent work)
  const int gthreads = NWG_A * A_THREADS;
  for (int i = wg * A_THREADS + tid; i < (N_NODES * N_FEAT) / 4; i += gthreads) {
    float4 f = ((const float4*)x)[i];
    uint2 o;
    o.x = f2bf(__float_as_uint(f.x)) | (f2bf(__float_as_uint(f.y)) << 16);
    o.y = f2bf(__float_as_uint(f.z)) | (f2bf(__float_as_uint(f.w)) << 16);
    ((uint2*)xb)[i] = o;
  }
  __syncthreads();

  // phase 1: per-bucket histogram of this wg's slice
  int e0 = wg * EPW;
  int e1 = e0 + EPW;
  for (int e = e0 + tid; e < e1; e += A_THREADS) {
    if (!edge_keep((uint32_t)e)) continue;
    atomicAdd(&cnt[(uint32_t)row[e] >> RSHIFT], 1u);
  }
  __syncthreads();

  // phase 2: LDS inclusive scan over NB counts -> dense per-bucket bases
  if (tid < NB) s[tid] = cnt[tid];
  __syncthreads();
  for (int off = 1; off < 256; off <<= 1) {
    uint32_t v = 0, u = 0;
    if (tid < NB) {
      v = s[tid];
      u = (tid >= off) ? s[tid - off] : 0u;
    }
    __syncthreads();
    if (tid < NB) s[tid] = v + u;
    __syncthreads();
  }
  if (tid < NB) {
    uint32_t bb = s[tid] - cnt[tid];  // exclusive prefix
    base[tid] = bb;
    lens[(size_t)tid * NWG_A + wg] = cnt[tid];
    segbase[(size_t)tid * NWG_A + wg] = bb;
  }
  __syncthreads();

  // phase 3: re-iterate, place densely into this wg's private window
  uint64_t* my = coarse + (size_t)wg * CSTRIDE;
  for (int e = e0 + tid; e < e1; e += A_THREADS) {
    if (!edge_keep((uint32_t)e)) continue;
    float v = adj_vals[e] / 0.9f;
    uint32_t r = (uint32_t)row[e];
    uint32_t c = (uint32_t)col[e];
    uint32_t b = r >> RSHIFT;
    uint32_t pos = base[b] + atomicAdd(&fill[b], 1u);
    my[pos] = ((uint64_t)r << 48) | ((uint64_t)c << 32) | (uint64_t)__float_as_uint(v);
  }
}

// Pass B (R8-proven structure): one 1024-thread wg per 256-row bucket; 4 threads
// per source segment place entries into per-row payload slots (64 KB L2-resident
// window). Rows zero-padded to a multiple of 8 for the branchless gather.
__global__ void __launch_bounds__(1024) partB_kernel(const uint64_t* __restrict__ coarse,
                                                     const uint32_t* __restrict__ lens,
                                                     const uint32_t* __restrict__ segbase,
                                                     uint32_t* __restrict__ payload,
                                                     uint32_t* __restrict__ cursor,
                                                     uint32_t* __restrict__ ovf_count,
                                                     uint64_t* __restrict__ ovf) {
  __shared__ uint32_t cnt[BROWS];
  int b = blockIdx.x;
  int tid = threadIdx.x;
  if (tid < BROWS) cnt[tid] = 0;
  __syncthreads();
  int seg = tid >> 2;   // source wg index, 256 segments
  int sub = tid & 3;
  uint32_t slen = lens[(size_t)b * NWG_A + seg];
  const uint64_t* cseg = coarse + (size_t)seg * CSTRIDE + segbase[(size_t)b * NWG_A + seg];
  for (uint32_t li = (uint32_t)sub; li < slen; li += 4) {
    uint64_t p = cseg[li];
    uint32_t r = (uint32_t)(p >> 48);
    uint32_t rl = r & (BROWS - 1);
    uint32_t idx = atomicAdd(&cnt[rl], 1u);
    if (idx < CAP) {
      uint32_t c = (uint32_t)(p >> 32) & 0xFFFFu;
      payload[(size_t)r * CAP + idx] = (c << 16) | f2bf((uint32_t)p);
    } else {
      uint32_t oi = atomicAdd(ovf_count, 1u);
      if (oi < OVF_CAP) ovf[oi] = p;   // +6.5 sigma; statistically never
    }
  }
  __syncthreads();
  // finalize cursors; zero-pad each row's slots to a multiple of 8
  for (int k = tid; k < BROWS; k += 1024) {
    uint32_t r = ((uint32_t)b << RSHIFT) + (uint32_t)k;
    if (r < N_NODES) {
      uint32_t c0 = min(cnt[k], (uint32_t)CAP);
      cursor[r] = r * CAP + c0;
      uint32_t np = min((c0 + 7u) & ~7u, (uint32_t)CAP);
      for (uint32_t i2 = c0; i2 < np; ++i2) payload[(size_t)r * CAP + i2] = 0u;
    }
  }
}

// Gather from bf16 x (R8-proven, verbatim): 32-lane teams per row, 8 teams/block.
__global__ void __launch_bounds__(256) gather_bf16_kernel(const uint32_t* __restrict__ xb,
                                                          const uint32_t* __restrict__ payload,
                                                          const uint32_t* __restrict__ cursor,
                                                          float* __restrict__ out) {
  int r = blockIdx.x * 8 + (threadIdx.x >> 5);
  int lane = threadIdx.x & 31;
  uint32_t base = (uint32_t)r * CAP;
  uint32_t cnt = cursor[r] - base;            // true count, <= CAP
  uint32_t n = (cnt + 7u) & ~7u;              // padded count; pads are zeros
  const uint2* x2 = (const uint2*)xb;         // row stride: 32 uint2 (128 bf16)
  float4 acc = make_float4(0.f, 0.f, 0.f, 0.f);

  uint32_t p = payload[base + lane];          // coalesced; one load covers 32 slots

#define GSTEP(ww)                                                            \
  {                                                                          \
    uint32_t cc = (ww) >> 16;                                                \
    float vv = __uint_as_float((ww) << 16);                                  \
    uint2 a = x2[(size_t)cc * 32 + lane];                                    \
    acc.x += vv * __uint_as_float(a.x << 16);                                \
    acc.y += vv * __uint_as_float(a.x & 0xffff0000u);                        \
    acc.z += vv * __uint_as_float(a.y << 16);                                \
    acc.w += vv * __uint_as_float(a.y & 0xffff0000u);                        \
  }

  int n0 = (int)min(n, 32u);
  for (int j = 0; j < n0; j += 8) {
    uint32_t w0 = __shfl(p, j + 0, 32);
    uint32_t w1 = __shfl(p, j + 1, 32);
    uint32_t w2 = __shfl(p, j + 2, 32);
    uint32_t w3 = __shfl(p, j + 3, 32);
    uint32_t w4 = __shfl(p, j + 4, 32);
    uint32_t w5 = __shfl(p, j + 5, 32);
    uint32_t w6 = __shfl(p, j + 6, 32);
    uint32_t w7 = __shfl(p, j + 7, 32);
    GSTEP(w0) GSTEP(w1) GSTEP(w2) GSTEP(w3)
    GSTEP(w4) GSTEP(w5) GSTEP(w6) GSTEP(w7)
  }
  if (n > 32) {
    uint32_t q = payload[base + 32 + lane];
    int n1 = (int)(n - 32u);
    for (int j = 0; j < n1; j += 8) {
      uint32_t w0 = __shfl(q, j + 0, 32);
      uint32_t w1 = __shfl(q, j + 1, 32);
      uint32_t w2 = __shfl(q, j + 2, 32);
      uint32_t w3 = __shfl(q, j + 3, 32);
      uint32_t w4 = __shfl(q, j + 4, 32);
      uint32_t w5 = __shfl(q, j + 5, 32);
      uint32_t w6 = __shfl(q, j + 6, 32);
      uint32_t w7 = __shfl(q, j + 7, 32);
      GSTEP(w0) GSTEP(w1) GSTEP(w2) GSTEP(w3)
      GSTEP(w4) GSTEP(w5) GSTEP(w6) GSTEP(w7)
    }
  }
#undef GSTEP
  ((float4*)out)[(size_t)r * 32 + lane] = acc;  // writes every row: no d_out memset
}

// exact cleanup for packed (row,col,f32val) overflow entries (expected: none)
__global__ void __launch_bounds__(256) ovf_pack_kernel(const float* __restrict__ x,
                                                       const uint32_t* __restrict__ ovf_count,
                                                       const uint64_t* __restrict__ ovf,
                                                       float* __restrict__ out) {
  uint32_t n = *ovf_count;
  if (n > OVF_CAP) n = OVF_CAP;
  int g = (int)((blockIdx.x * blockDim.x + threadIdx.x) >> 7);
  int f = threadIdx.x & 127;
  const int ngroups = (64 * 256) >> 7;
  for (uint32_t oi = g; oi < n; oi += ngroups) {
    uint64_t p = ovf[oi];
    uint32_t r = (uint32_t)(p >> 48);
    uint32_t c = (uint32_t)((p >> 32) & 0xFFFFu);
    float v = __uint_as_float((uint32_t)p);
    atomicAdd(&out[(size_t)r * N_FEAT + f], v * x[(size_t)c * N_FEAT + f]);
  }
}

// =================== FALLBACK: fused atomic scatter ============================

__global__ void __launch_bounds__(256) scatter_fused_kernel(const float* __restrict__ x,
                                                            const float* __restrict__ adj_vals,
                                                            const int* __restrict__ row,
                                                            const int* __restrict__ col,
                                                            float* __restrict__ out) {
  long long t = (long long)blockIdx.x * blockDim.x + threadIdx.x;
  int e = (int)(t >> 6);
  int lane = (int)(t & 63);
  if (e >= N_EDGES) return;
  if (!edge_keep((uint32_t)e)) return;
  float v = adj_vals[e] / 0.9f;
  float2 xf = *(const float2*)(x + (long long)col[e] * N_FEAT + lane * 2);
  float* dst = out + (long long)row[e] * N_FEAT + lane * 2;
  atomicAdd(dst, v * xf.x);
  atomicAdd(dst + 1, v * xf.y);
}

// ---------------- launch --------------------------------------------------------

extern "C" void kernel_launch(void* const* d_in, const int* in_sizes, int n_in,
                              void* d_out, int out_size, void* d_ws, size_t ws_size,
                              hipStream_t stream) {
  const float* x        = (const float*)d_in[0];
  const float* adj_vals = (const float*)d_in[1];
  const int*   row      = (const int*)d_in[2];
  const int*   col      = (const int*)d_in[3];
  float* out = (float*)d_out;

  // ---- workspace layout ----
  size_t a_ovfc    = 0;                                                    // 1 u32
  size_t a_ovf     = (a_ovfc + 4 + 255) & ~255ull;                         // OVF_CAP u64
  size_t a_lens    = (a_ovf + (size_t)OVF_CAP * 8 + 255) & ~255ull;        // NB*NWG_A u32
  size_t a_segb    = (a_lens + (size_t)NB * NWG_A * 4 + 255) & ~255ull;    // NB*NWG_A u32
  size_t a_cursor  = (a_segb + (size_t)NB * NWG_A * 4 + 255) & ~255ull;    // N u32
  size_t a_coarse  = (a_cursor + (size_t)N_NODES * 4 + 255) & ~255ull;     // NWG_A*CSTRIDE u64
  size_t a_payload = (a_coarse + (size_t)NWG_A * CSTRIDE * 8 + 255) & ~255ull;  // N*CAP u32
  size_t a_xb      = (a_payload + (size_t)N_NODES * CAP * 4 + 255) & ~255ull;   // N*F bf16
  size_t need      = a_xb + (size_t)N_NODES * N_FEAT * 2;                  // ~39.6 MB

  if (ws_size >= need) {
    uint32_t* ovf_count = (uint32_t*)((char*)d_ws + a_ovfc);
    uint64_t* ovf       = (uint64_t*)((char*)d_ws + a_ovf);
    uint32_t* lens      = (uint32_t*)((char*)d_ws + a_lens);
    uint32_t* segbase   = (uint32_t*)((char*)d_ws + a_segb);
    uint32_t* cursor    = (uint32_t*)((char*)d_ws + a_cursor);
    uint64_t* coarse    = (uint64_t*)((char*)d_ws + a_coarse);
    uint32_t* payload   = (uint32_t*)((char*)d_ws + a_payload);
    uint32_t* xb        = (uint32_t*)((char*)d_ws + a_xb);

    hipMemsetAsync(ovf_count, 0, 4, stream);
    convA_kernel<<<NWG_A, A_THREADS, 0, stream>>>(x, xb, adj_vals, row, col,
                                                  coarse, lens, segbase);
    partB_kernel<<<NB, 1024, 0, stream>>>(coarse, lens, segbase, payload, cursor,
                                          ovf_count, ovf);
    gather_bf16_kernel<<<N_NODES / 8, 256, 0, stream>>>(xb, payload, cursor, out);
    ovf_pack_kernel<<<64, 256, 0, stream>>>(x, ovf_count, ovf, out);
  } else {
    hipMemsetAsync(d_out, 0, (size_t)out_size * sizeof(float), stream);
    long long total_threads = (long long)N_EDGES * 64;
    scatter_fused_kernel<<<(int)((total_threads + 255) / 256), 256, 0, stream>>>(
        x, adj_vals, row, col, out);
  }
}